// Round 15
// baseline (245.520 us; speedup 1.0000x reference)
//
#include <hip/hip_runtime.h>
#include <stdint.h>

typedef __bf16 bf16x8 __attribute__((ext_vector_type(8)));
typedef float f32x4 __attribute__((ext_vector_type(4)));
typedef float f32x16 __attribute__((ext_vector_type(16)));
typedef unsigned short u16;
typedef unsigned int u32;
typedef unsigned int u32x2 __attribute__((ext_vector_type(2)));

__device__ __forceinline__ u16 f2bf(float f) {
    u32 u = __builtin_bit_cast(u32, f);
    u = (u + 0x7fffu + ((u >> 16) & 1u)) >> 16;
    return (u16)u;
}
__device__ __forceinline__ float bf2f(u16 x) {
    return __builtin_bit_cast(float, (u32)x << 16);
}
__device__ __forceinline__ float fexp2(float x) {
#if __has_builtin(__builtin_amdgcn_exp2f)
    return __builtin_amdgcn_exp2f(x);
#else
    return exp2f(x);
#endif
}
__device__ __forceinline__ void plswap(u32& a, u32& b) {
#if __has_builtin(__builtin_amdgcn_permlane32_swap)
    u32x2 r = __builtin_amdgcn_permlane32_swap(a, b, false, false);
    a = r[0]; b = r[1];
#else
    asm volatile("v_permlane32_swap_b32 %0, %1" : "+v"(a), "+v"(b));
#endif
}

__device__ __forceinline__ void gload16(const u16* g, u16* l) {
    __builtin_amdgcn_global_load_lds(
        (const __attribute__((address_space(1))) unsigned int*)g,
        (__attribute__((address_space(3))) unsigned int*)l,
        16, 0, 0);
}

// chunk maps for split-k attention: per bh, 72 uniform chunks (<=4 stages of 64 k)
__device__ __constant__ unsigned char QB2[72] = {
    0,1,2,2,3,3,4,4,4,5,5,5,6,6,6,6,7,7,7,7,
    8,8,8,8,8,9,9,9,9,9,10,10,10,10,10,10,11,11,11,11,11,11,
    12,12,12,12,12,12,12,13,13,13,13,13,13,13,
    14,14,14,14,14,14,14,14,15,15,15,15,15,15,15,15};
__device__ __constant__ unsigned char CH2[72] = {
    0,0,0,1,0,1,0,1,2,0,1,2,0,1,2,3,0,1,2,3,
    0,1,2,3,4,0,1,2,3,4,0,1,2,3,4,5,0,1,2,3,4,5,
    0,1,2,3,4,5,6,0,1,2,3,4,5,6,
    0,1,2,3,4,5,6,7,0,1,2,3,4,5,6,7};
__device__ __constant__ unsigned char CUM2[17] =
    {0,1,2,4,6,9,12,16,20,25,30,36,42,49,56,64,72};

// ---------------- fused prep: 5 weight transposes + LN1 ----------------
__global__ __launch_bounds__(256)
void prep_all(const float* __restrict__ Wq, const float* __restrict__ Wk,
              const float* __restrict__ Wproj, const float* __restrict__ W1,
              const float* __restrict__ W2,
              u16* __restrict__ wqkT, u16* __restrict__ wprojT,
              u16* __restrict__ w1T, u16* __restrict__ w2T,
              const float* __restrict__ x, const float* __restrict__ g1,
              const float* __restrict__ b1v, u16* __restrict__ hbuf) {
    __shared__ u16 tile[64 * 64];
    __shared__ float red[8];
    const int bid = blockIdx.x;
    const int t = threadIdx.x;
    if (bid >= 2816) {   // LN1 rows
        const int row = bid - 2816;
        float4 v = reinterpret_cast<const float4*>(x + (size_t)row * 1024)[t];
        float s = v.x + v.y + v.z + v.w;
        float sq = v.x * v.x + v.y * v.y + v.z * v.z + v.w * v.w;
        for (int o = 32; o > 0; o >>= 1) { s += __shfl_down(s, o); sq += __shfl_down(sq, o); }
        if ((t & 63) == 0) { red[t >> 6] = s; red[4 + (t >> 6)] = sq; }
        __syncthreads();
        float S  = red[0] + red[1] + red[2] + red[3];
        float SQ = red[4] + red[5] + red[6] + red[7];
        float mean = S * (1.f / 1024.f);
        float var  = SQ * (1.f / 1024.f) - mean * mean;
        float rstd = rsqrtf(var + 1e-5f);
        float4 g4 = reinterpret_cast<const float4*>(g1)[t];
        float4 b4 = reinterpret_cast<const float4*>(b1v)[t];
        ushort4 o;
        o.x = f2bf((v.x - mean) * rstd * g4.x + b4.x);
        o.y = f2bf((v.y - mean) * rstd * g4.y + b4.y);
        o.z = f2bf((v.z - mean) * rstd * g4.z + b4.z);
        o.w = f2bf((v.w - mean) * rstd * g4.w + b4.w);
        reinterpret_cast<ushort4*>(hbuf + (size_t)row * 1024)[t] = o;
        return;
    }
    const float* src; u16* dst; int R, C, c0, r0; size_t zb = 0;
    if (bid < 512) {
        const int q = bid & 255; const int z = q >> 4;
        src = (bid < 256) ? Wq : Wk;
        dst = (bid < 256) ? wqkT : (wqkT + 1048576);
        R = 1024; C = 64; c0 = 0; r0 = (q & 15) * 64; zb = (size_t)z * 65536;
    } else if (bid < 768) {
        const int q = bid - 512; src = Wproj; dst = wprojT; R = 1024; C = 1024;
        c0 = (q & 15) * 64; r0 = (q >> 4) * 64;
    } else if (bid < 1792) {
        const int q = bid - 768; src = W1; dst = w1T; R = 1024; C = 4096;
        c0 = (q & 63) * 64; r0 = (q >> 6) * 64;
    } else {
        const int q = bid - 1792; src = W2; dst = w2T; R = 4096; C = 1024;
        c0 = (q & 15) * 64; r0 = (q >> 4) * 64;
    }
    {
        const int r = t >> 2, j4 = t & 3;
        #pragma unroll
        for (int j = 0; j < 4; ++j) {
            int c = j4 * 4 + j * 16;
            float4 v = *reinterpret_cast<const float4*>(src + zb + (size_t)(r0 + r) * C + c0 + c);
            tile[(c + 0) * 64 + (r ^ (((c + 0) & 7) * 8))] = f2bf(v.x);
            tile[(c + 1) * 64 + (r ^ (((c + 1) & 7) * 8))] = f2bf(v.y);
            tile[(c + 2) * 64 + (r ^ (((c + 2) & 7) * 8))] = f2bf(v.z);
            tile[(c + 3) * 64 + (r ^ (((c + 3) & 7) * 8))] = f2bf(v.w);
        }
    }
    __syncthreads();
    {
        const int cc = t >> 2, j4 = t & 3;
        const int sw = (cc & 7) * 8;
        #pragma unroll
        for (int j2 = 0; j2 < 4; ++j2) {
            int rbase = j4 * 16 + j2 * 4;
            ushort4 o;
            o.x = tile[cc * 64 + ((rbase + 0) ^ sw)];
            o.y = tile[cc * 64 + ((rbase + 1) ^ sw)];
            o.z = tile[cc * 64 + ((rbase + 2) ^ sw)];
            o.w = tile[cc * 64 + ((rbase + 3) ^ sw)];
            *reinterpret_cast<ushort4*>(dst + zb + (size_t)(c0 + cc) * R + r0 + rbase) = o;
        }
    }
}

// ---------------- layernorm (fallback LN2) ----------------
__global__ __launch_bounds__(256)
void ln_kernel(const float* __restrict__ x, u16* __restrict__ out,
               const float* __restrict__ gw, const float* __restrict__ bw) {
    __shared__ float red[8];
    int row = blockIdx.x, t = threadIdx.x;
    float4 v = reinterpret_cast<const float4*>(x + (size_t)row * 1024)[t];
    float s = v.x + v.y + v.z + v.w;
    float sq = v.x * v.x + v.y * v.y + v.z * v.z + v.w * v.w;
    for (int o = 32; o > 0; o >>= 1) { s += __shfl_down(s, o); sq += __shfl_down(sq, o); }
    if ((t & 63) == 0) { red[t >> 6] = s; red[4 + (t >> 6)] = sq; }
    __syncthreads();
    float S  = red[0] + red[1] + red[2] + red[3];
    float SQ = red[4] + red[5] + red[6] + red[7];
    float mean = S * (1.f / 1024.f);
    float var  = SQ * (1.f / 1024.f) - mean * mean;
    float rstd = rsqrtf(var + 1e-5f);
    float4 g4 = reinterpret_cast<const float4*>(gw)[t];
    float4 b4 = reinterpret_cast<const float4*>(bw)[t];
    ushort4 o;
    o.x = f2bf((v.x - mean) * rstd * g4.x + b4.x);
    o.y = f2bf((v.y - mean) * rstd * g4.y + b4.y);
    o.z = f2bf((v.z - mean) * rstd * g4.z + b4.z);
    o.w = f2bf((v.w - mean) * rstd * g4.w + b4.w);
    reinterpret_cast<ushort4*>(out + (size_t)row * 1024)[t] = o;
}

// ---------------- fused: xmid = bf16(p0)+bf16(p1)+x+bproj ; LN2 -> hbuf bf16 ----------------
__global__ __launch_bounds__(256)
void ln2red_kernel(const u16* __restrict__ p0, const u16* __restrict__ p1,
                   const float4* __restrict__ x4, const float* __restrict__ bproj,
                   const float* __restrict__ gw, const float* __restrict__ bw,
                   float4* __restrict__ xmid, u16* __restrict__ out) {
    __shared__ float red[8];
    const int row = blockIdx.x, t = threadIdx.x;
    const size_t idx = (size_t)row * 256 + t;
    const ushort4 a4 = *reinterpret_cast<const ushort4*>(p0 + idx * 4);
    const ushort4 b4u = *reinterpret_cast<const ushort4*>(p1 + idx * 4);
    float4 xx = x4[idx];
    const float4 bp = *reinterpret_cast<const float4*>(bproj + (t << 2));
    float4 v;
    v.x = bf2f(a4.x) + bf2f(b4u.x) + xx.x + bp.x;
    v.y = bf2f(a4.y) + bf2f(b4u.y) + xx.y + bp.y;
    v.z = bf2f(a4.z) + bf2f(b4u.z) + xx.z + bp.z;
    v.w = bf2f(a4.w) + bf2f(b4u.w) + xx.w + bp.w;
    xmid[idx] = v;
    float s = v.x + v.y + v.z + v.w;
    float sq = v.x * v.x + v.y * v.y + v.z * v.z + v.w * v.w;
    for (int o = 32; o > 0; o >>= 1) { s += __shfl_down(s, o); sq += __shfl_down(sq, o); }
    if ((t & 63) == 0) { red[t >> 6] = s; red[4 + (t >> 6)] = sq; }
    __syncthreads();
    float S  = red[0] + red[1] + red[2] + red[3];
    float SQ = red[4] + red[5] + red[6] + red[7];
    float mean = S * (1.f / 1024.f);
    float var  = SQ * (1.f / 1024.f) - mean * mean;
    float rstd = rsqrtf(var + 1e-5f);
    const float4 g4 = *reinterpret_cast<const float4*>(gw + (t << 2));
    const float4 b4 = *reinterpret_cast<const float4*>(bw + (t << 2));
    ushort4 o;
    o.x = f2bf((v.x - mean) * rstd * g4.x + b4.x);
    o.y = f2bf((v.y - mean) * rstd * g4.y + b4.y);
    o.z = f2bf((v.z - mean) * rstd * g4.z + b4.z);
    o.w = f2bf((v.w - mean) * rstd * g4.w + b4.w);
    *reinterpret_cast<ushort4*>(out + idx * 4) = o;
}

// ---------------- 128x128 GEMM (fallback only) ----------------
template<int EPI, typename OT>
__global__ __launch_bounds__(256)
void gemm_bt(const u16* __restrict__ A, const u16* __restrict__ B,
             OT* __restrict__ C, const float* __restrict__ bias,
             const float* __restrict__ res, int K, int N, u16* __restrict__ ktr) {
    __shared__ u16 Al[128 * 64];
    __shared__ u16 Bl[128 * 64];
    const int t = threadIdx.x;
    const int lane = t & 63;
    const int w = t >> 6;
    const int wm = w >> 1, wn = w & 1;
    const int l15 = lane & 15, gq = lane >> 4;
    const int gx = gridDim.x;
    const int nwg = gx * gridDim.y;
    const int bid = blockIdx.y * gx + blockIdx.x;
    const int sw = ((nwg & 7) == 0) ? ((bid & 7) * (nwg >> 3) + (bid >> 3)) : bid;
    const int col0 = (sw % gx) * 128;
    const int row0 = (sw / gx) * 128;

    f32x4 acc[4][4] = {};

    const int nkb = K >> 6;
    for (int kb = 0; kb < nkb; ++kb) {
        #pragma unroll
        for (int i = 0; i < 4; ++i) {
            int slot = i * 256 + t;
            int r = slot >> 3;
            int g = (slot & 7) ^ (r & 7);
            gload16(A + (size_t)(row0 + r) * K + kb * 64 + g * 8, Al + slot * 8);
            gload16(B + (size_t)(col0 + r) * K + kb * 64 + g * 8, Bl + slot * 8);
        }
        __syncthreads();
        #pragma unroll
        for (int s = 0; s < 2; ++s) {
            bf16x8 af[4], bfr[4];
            #pragma unroll
            for (int mi = 0; mi < 4; ++mi) {
                int rl = wm * 64 + mi * 16 + l15;
                int ba = rl * 128 + ((s * 64 + gq * 16) ^ ((rl & 7) << 4));
                af[mi] = *reinterpret_cast<const bf16x8*>(reinterpret_cast<const char*>(Al) + ba);
            }
            #pragma unroll
            for (int ni = 0; ni < 4; ++ni) {
                int rl = wn * 64 + ni * 16 + l15;
                int ba = rl * 128 + ((s * 64 + gq * 16) ^ ((rl & 7) << 4));
                bfr[ni] = *reinterpret_cast<const bf16x8*>(reinterpret_cast<const char*>(Bl) + ba);
            }
            #pragma unroll
            for (int mi = 0; mi < 4; ++mi)
                #pragma unroll
                for (int ni = 0; ni < 4; ++ni)
                    acc[mi][ni] = __builtin_amdgcn_mfma_f32_16x16x32_bf16(af[mi], bfr[ni], acc[mi][ni], 0, 0, 0);
        }
        __syncthreads();
    }

    #pragma unroll
    for (int mi = 0; mi < 4; ++mi) {
        #pragma unroll
        for (int ni = 0; ni < 4; ++ni) {
            int gcol = col0 + wn * 64 + ni * 16 + l15;
            int grow0 = row0 + wm * 64 + mi * 16 + gq * 4;
            #pragma unroll
            for (int r = 0; r < 4; ++r) {
                int grow = grow0 + r;
                float v = acc[mi][ni][r];
                if constexpr (EPI == 1 || EPI == 2) v += bias[gcol];
                if constexpr (EPI == 1) v += res[(size_t)grow * N + gcol];
                if constexpr (EPI == 2) v = fmaxf(v, 0.f);
                if constexpr (sizeof(OT) == 4) C[(size_t)grow * N + gcol] = v;
                else                           C[(size_t)grow * N + gcol] = f2bf(v);
            }
        }
    }
}

// ---------------- shared macros for fine-phased GEMMs ----------------
#define DS_A(MH) \
  _Pragma("unroll") \
  for (int mi = 0; mi < 4; ++mi) { \
    const int rl = wm * 128 + (MH) * 64 + mi * 16 + l15; \
    const char* rp = abase + rl * 128; \
    const int sw2 = (rl & 7) << 4; \
    af[mi][0] = *reinterpret_cast<const bf16x8*>(rp + ((gq * 16) ^ sw2)); \
    af[mi][1] = *reinterpret_cast<const bf16x8*>(rp + ((64 + gq * 16) ^ sw2)); \
  }

#define DS_B(NH) \
  _Pragma("unroll") \
  for (int ni = 0; ni < 2; ++ni) { \
    const int rl = wn * 64 + (NH) * 32 + ni * 16 + l15; \
    const char* rp = bbase + rl * 128; \
    const int sw2 = (rl & 7) << 4; \
    bfr[NH][ni][0] = *reinterpret_cast<const bf16x8*>(rp + ((gq * 16) ^ sw2)); \
    bfr[NH][ni][1] = *reinterpret_cast<const bf16x8*>(rp + ((64 + gq * 16) ^ sw2)); \
  }

#define ST_A(HALF, KP, DB) \
  _Pragma("unroll") \
  for (int i = 0; i < 2; ++i) { \
    const int idx = i * 512 + t; const int rs = idx >> 3; const int kc = idx & 7; \
    const int row = (rs & 63) + ((rs >> 6) << 7) + (HALF) * 64; \
    gload16(Ag + (size_t)(row0 + row) * Kf + (KP) + ((kc ^ (row & 7)) << 3), (DB) + row * 64 + kc * 8); \
  }

#define ST_B(HALF, KP, DB) \
  _Pragma("unroll") \
  for (int i = 0; i < 2; ++i) { \
    const int idx = i * 512 + t; const int rs = idx >> 3; const int kc = idx & 7; \
    const int row = (rs & 31) + ((rs >> 5) << 6) + (HALF) * 32; \
    gload16(Bg + (size_t)(col0 + row) * Kf + (KP) + ((kc ^ (row & 7)) << 3), (DB) + row * 64 + kc * 8); \
  }

#define MFMA_Q(MH, NH) \
  _Pragma("unroll") \
  for (int mi = 0; mi < 4; ++mi) { \
    _Pragma("unroll") \
    for (int ni = 0; ni < 2; ++ni) { \
      acc[MH][mi][NH][ni] = __builtin_amdgcn_mfma_f32_16x16x32_bf16(af[mi][0], bfr[NH][ni][0], acc[MH][mi][NH][ni], 0, 0, 0); \
      acc[MH][mi][NH][ni] = __builtin_amdgcn_mfma_f32_16x16x32_bf16(af[mi][1], bfr[NH][ni][1], acc[MH][mi][NH][ni], 0, 0, 0); \
    } \
  }

#define WAITV(N) asm volatile("s_waitcnt vmcnt(" #N ")" ::: "memory")
#define BAR() __builtin_amdgcn_s_barrier()
#define PRIO1() __builtin_amdgcn_s_setprio(1)
#define PRIO0() __builtin_amdgcn_s_setprio(0)

// rect-tiled XCD mapping: each XCD's chunk covers a rectangle (L2 locality)
__device__ __forceinline__ void xcd_rect(int bid, int gx, int nwg, int& colI, int& rowI) {
    if (nwg == 256 && gx == 16) {            // 4 cols x 8 rows per XCD
        const int xcd = bid & 7, k = bid >> 3;
        colI = (xcd & 3) * 4 + (k & 3);
        rowI = (xcd >> 2) * 8 + (k >> 2);
    } else if (nwg == 128 && gx == 8) {      // 2 cols x 8 rows per XCD
        const int xcd = bid & 7, k = bid >> 3;
        colI = (xcd & 3) * 2 + (k & 1);
        rowI = (xcd >> 2) * 8 + (k >> 1);
    } else {
        const int sw = ((nwg & 7) == 0) ? ((bid & 7) * (nwg >> 3) + (bid >> 3)) : bid;
        colI = sw % gx; rowI = sw / gx;
    }
}

// ---------------- 256x256 fine-phased GEMM (R8 schedule, B-resident) ----------------
template<int EPI, typename OT>
__global__ __launch_bounds__(512, 2)
void gemm256(const u16* __restrict__ A, const u16* __restrict__ B, OT* __restrict__ C,
             const float* __restrict__ bias, const float* __restrict__ res,
             int Kf, int KC, int N, u16* __restrict__ ktr) {
    __shared__ u16 AL[2][16384];
    __shared__ u16 BL[2][16384];
    const int t = threadIdx.x;
    const int lane = t & 63;
    const int w = t >> 6;
    const int wm = w >> 2, wn = w & 3;
    const int l15 = lane & 15, gq = lane >> 4;
    const int gx = gridDim.x;
    const int nwg = gx * gridDim.y;
    const int bid = blockIdx.y * gx + blockIdx.x;
    int colI, rowI;
    xcd_rect(bid, gx, nwg, colI, rowI);
    const int col0 = colI * 256;
    const int row0 = rowI * 256;
    const int kbase = blockIdx.z * KC;
    const u16* Ag = A;
    const u16* Bg = B;

    f32x4 acc[2][4][2][2] = {};
    bf16x8 af[4][2], bfr[2][2][2];

    const int NT = KC >> 6;
    { u16* An = &AL[0][0]; u16* Bn = &BL[0][0];
      ST_A(0, kbase, An); ST_B(0, kbase, Bn); ST_B(1, kbase, Bn); ST_A(1, kbase, An); }
    WAITV(4);
    BAR();

    for (int tI = 0; tI < NT - 1; ++tI) {
        const int c = tI & 1;
        const char* abase = reinterpret_cast<const char*>(&AL[c][0]);
        const char* bbase = reinterpret_cast<const char*>(&BL[c][0]);
        u16* An = &AL[c ^ 1][0];
        u16* Bn = &BL[c ^ 1][0];
        const int kn = kbase + (tI + 1) * 64;
        // ph1
        DS_A(0); DS_B(0);
        ST_A(0, kn, An);
        WAITV(4); BAR();
        PRIO1(); MFMA_Q(0, 0); PRIO0();
        BAR();
        // ph2
        DS_B(1);
        ST_B(0, kn, Bn);
        WAITV(4); BAR();
        PRIO1(); MFMA_Q(0, 1); PRIO0();
        BAR();
        // ph3 (B half 0 resident in bfr[0])
        DS_A(1);
        ST_B(1, kn, Bn);
        BAR();
        PRIO1(); MFMA_Q(1, 0); PRIO0();
        BAR();
        // ph4 (B half 1 resident in bfr[1])
        ST_A(1, kn, An);
        WAITV(4); BAR();
        PRIO1(); MFMA_Q(1, 1); PRIO0();
        BAR();
    }
    {   // peeled last tile
        const int c = (NT - 1) & 1;
        const char* abase = reinterpret_cast<const char*>(&AL[c][0]);
        const char* bbase = reinterpret_cast<const char*>(&BL[c][0]);
        DS_A(0); DS_B(0);
        WAITV(2); BAR();
        PRIO1(); MFMA_Q(0, 0); PRIO0();
        BAR();
        DS_B(1);
        WAITV(0); BAR();
        PRIO1(); MFMA_Q(0, 1); PRIO0();
        BAR();
        DS_A(1);
        BAR();
        PRIO1(); MFMA_Q(1, 0); PRIO0();
        BAR();
        PRIO1(); MFMA_Q(1, 1); PRIO0();
    }

    const size_t Crow0 = (size_t)blockIdx.z * ((size_t)gridDim.y * 256);
    #pragma unroll
    for (int mh = 0; mh < 2; ++mh)
    #pragma unroll
    for (int mi = 0; mi < 4; ++mi)
    #pragma unroll
    for (int nh = 0; nh < 2; ++nh)
    #pragma unroll
    for (int ni = 0; ni < 2; ++ni) {
        const int gcol = col0 + wn * 64 + nh * 32 + ni * 16 + l15;
        const int grow0 = row0 + wm * 128 + mh * 64 + mi * 16 + gq * 4;
        f32x4 v = acc[mh][mi][nh][ni];
        if constexpr (EPI == 2) {
            const float bb = bias[gcol];
            v[0] += bb; v[1] += bb; v[2] += bb; v[3] += bb;
        }
        #pragma unroll
        for (int r = 0; r < 4; ++r) {
            const size_t o = (Crow0 + grow0 + r) * N + gcol;
            float x = v[r];
            if constexpr (EPI == 2) x = fmaxf(x, 0.f);
            if constexpr (sizeof(OT) == 4) C[o] = x;
            else                           C[o] = f2bf(x);
        }
    }
}

// ---------------- 256x128 fine-phased GEMM (R8 schedule) ----------------
#define DS_B2 \
  _Pragma("unroll") \
  for (int ni = 0; ni < 2; ++ni) { \
    const int rl = wn * 32 + ni * 16 + l15; \
    const char* rp = bbase + rl * 128; \
    const int sw2 = (rl & 7) << 4; \
    bfr[ni][0] = *reinterpret_cast<const bf16x8*>(rp + ((gq * 16) ^ sw2)); \
    bfr[ni][1] = *reinterpret_cast<const bf16x8*>(rp + ((64 + gq * 16) ^ sw2)); \
  }

#define ST_B2(KP, DB) \
  _Pragma("unroll") \
  for (int i = 0; i < 2; ++i) { \
    const int idx = i * 512 + t; const int rs = idx >> 3; const int kc = idx & 7; \
    gload16(Bg + (size_t)(col0 + rs) * Kf + (KP) + ((kc ^ (rs & 7)) << 3), (DB) + rs * 64 + kc * 8); \
  }

#define MFMA_Q2(MH) \
  _Pragma("unroll") \
  for (int mi = 0; mi < 4; ++mi) { \
    _Pragma("unroll") \
    for (int ni = 0; ni < 2; ++ni) { \
      acc[MH][mi][ni] = __builtin_amdgcn_mfma_f32_16x16x32_bf16(af[mi][0], bfr[ni][0], acc[MH][mi][ni], 0, 0, 0); \
      acc[MH][mi][ni] = __builtin_amdgcn_mfma_f32_16x16x32_bf16(af[mi][1], bfr[ni][1], acc[MH][mi][ni], 0, 0, 0); \
    } \
  }

template<int EPI, typename OT>
__global__ __launch_bounds__(512, 2)
void gemmN128(const u16* __restrict__ A, const u16* __restrict__ B, OT* __restrict__ C,
              int Kf, int KC, int N, u16* __restrict__ ktr) {
    __shared__ u16 AL[2][16384];   // 256 x 64
    __shared__ u16 BL[2][8192];    // 128 x 64
    const int t = threadIdx.x;
    const int lane = t & 63;
    const int w = t >> 6;
    const int wm = w >> 2, wn = w & 3;
    const int l15 = lane & 15, gq = lane >> 4;
    const int gx = gridDim.x;
    const int nwg = gx * gridDim.y;
    const int bid = blockIdx.y * gx + blockIdx.x;
    int colI, rowI;
    xcd_rect(bid, gx, nwg, colI, rowI);
    const int col0 = colI * 128;
    const int row0 = rowI * 256;
    const int kbase = blockIdx.z * KC;
    const u16* Ag = A;
    const u16* Bg = B;

    f32x4 acc[2][4][2] = {};
    bf16x8 af[4][2], bfr[2][2];

    const int NT = KC >> 6;
    { u16* An = &AL[0][0]; u16* Bn = &BL[0][0];
      ST_A(0, kbase, An); ST_B2(kbase, Bn); ST_A(1, kbase, An); }
    WAITV(0);
    BAR();

    for (int tI = 0; tI < NT - 1; ++tI) {
        const int c = tI & 1;
        const char* abase = reinterpret_cast<const char*>(&AL[c][0]);
        const char* bbase = reinterpret_cast<const char*>(&BL[c][0]);
        u16* An = &AL[c ^ 1][0];
        u16* Bn = &BL[c ^ 1][0];
        const int kn = kbase + (tI + 1) * 64;
        // ph1
        DS_A(0); DS_B2;
        ST_A(0, kn, An); ST_B2(kn, Bn);
        WAITV(4); BAR();
        PRIO1(); MFMA_Q2(0); PRIO0();
        BAR();
        // ph2
        DS_A(1);
        ST_A(1, kn, An);
        WAITV(2); BAR();
        PRIO1(); MFMA_Q2(1); PRIO0();
        BAR();
    }
    {   // peeled last tile
        const int c = (NT - 1) & 1;
        const char* abase = reinterpret_cast<const char*>(&AL[c][0]);
        const char* bbase = reinterpret_cast<const char*>(&BL[c][0]);
        DS_A(0); DS_B2;
        WAITV(0); BAR();
        PRIO1(); MFMA_Q2(0); PRIO0();
        BAR();
        DS_A(1);
        PRIO1(); MFMA_Q2(1); PRIO0();
    }

    const size_t Crow0 = (size_t)blockIdx.z * ((size_t)gridDim.y * 256);
    #pragma unroll
    for (int mh = 0; mh < 2; ++mh)
    #pragma unroll
    for (int mi = 0; mi < 4; ++mi)
    #pragma unroll
    for (int ni = 0; ni < 2; ++ni) {
        const int gcol = col0 + wn * 32 + ni * 16 + l15;
        const int grow0 = row0 + wm * 128 + mh * 64 + mi * 16 + gq * 4;
        f32x4 v = acc[mh][mi][ni];
        if constexpr (EPI == 3) {
            if (gcol < 1024) {   // Q columns: fold 1/sqrt(Dh) * log2(e) into Q
                const float QS = 0.18033688f;
                v[0] *= QS; v[1] *= QS; v[2] *= QS; v[3] *= QS;
            }
        }
        #pragma unroll
        for (int r = 0; r < 4; ++r) {
            const size_t o = (Crow0 + grow0 + r) * N + gcol;
            if constexpr (sizeof(OT) == 4) C[o] = v[r];
            else                           C[o] = f2bf(v[r]);
        }
        if constexpr (EPI == 3) {
            if (gcol >= 1024) {
                ushort4 k4;
                k4.x = f2bf(v[0]); k4.y = f2bf(v[1]); k4.z = f2bf(v[2]); k4.w = f2bf(v[3]);
                *reinterpret_cast<ushort4*>(ktr + (size_t)(gcol - 1024) * 4096 + grow0) = k4;
            }
        }
    }
}

// ---------------- split-K=2 reduce (bf16 partials): out = xmid + b2 + p0 + p1 ----------------
__global__ __launch_bounds__(256)
void reduce2_kernel(const u16* __restrict__ p0, const u16* __restrict__ p1,
                    const float4* __restrict__ xm, const float* __restrict__ b2,
                    float4* __restrict__ out) {
    const size_t i = (size_t)blockIdx.x * 256 + threadIdx.x;
    const ushort4 a4 = *reinterpret_cast<const ushort4*>(p0 + i * 4);
    const ushort4 b4 = *reinterpret_cast<const ushort4*>(p1 + i * 4);
    float4 x = xm[i];
    const float4 bb = *reinterpret_cast<const float4*>(b2 + ((threadIdx.x & 255) << 2));
    float4 o;
    o.x = x.x + bb.x + bf2f(a4.x) + bf2f(b4.x);
    o.y = x.y + bb.y + bf2f(a4.y) + bf2f(b4.y);
    o.z = x.z + bb.z + bf2f(a4.z) + bf2f(b4.z);
    o.w = x.w + bb.w + bf2f(a4.w) + bf2f(b4.w);
    out[i] = o;
}

// ---------------- causal flash attention, V == K, de-staged (L1/L2-direct) ----------------
// K block per (b,h) = 256 KB: L2-resident; all 4 waves read identical K/K^T lines -> L1 broadcast.
// No LDS, no barriers: waves fully independent, early break on causal mask.
template<int SPLIT>
__global__ __launch_bounds__(256)
void attn_kernel(const u16* __restrict__ qk, const u16* __restrict__ ktr, u16* __restrict__ out,
                 u16* __restrict__ pO, float* __restrict__ pl) {
    const int t = threadIdx.x;
    const int lane = t & 63;
    const int w = t >> 6;
    const int l31 = lane & 31, hi = lane >> 5;
    int bh, qb, npc, cid, s0, s1;
    if constexpr (SPLIT) {
        bh = blockIdx.x & 31;
        cid = blockIdx.x >> 5;
        qb = QB2[cid];
        const int ch = CH2[cid];
        npc = CUM2[qb + 1] - CUM2[qb];
        const int nt = 2 * (qb + 1);
        s0 = ch * 4;
        s1 = min(nt, s0 + 4);
    } else {
        bh = blockIdx.x & 31;
        const int tt = blockIdx.x >> 5;
        qb = (tt < 8) ? tt : 23 - tt;
        cid = 0; npc = 1; s0 = 0; s1 = 2 * (qb + 1);
    }
    const int b = bh >> 4, h = bh & 15;
    const int q0w = qb * 128 + w * 32;
    const int q = q0w + l31;
    const int qwmax = q0w + 31;
    const u16* Qp = qk + (size_t)b * 2048 * 2048 + h * 64;
    const u16* Kp = Qp + 1024;
    const u16* Tp = ktr + (size_t)h * 64 * 4096 + (size_t)b * 2048;

    bf16x8 qf[4];
    #pragma unroll
    for (int s = 0; s < 4; ++s)
        qf[s] = *reinterpret_cast<const bf16x8*>(Qp + (size_t)q * 2048 + s * 16 + hi * 8);

    f32x16 oacc[2] = {};
    float lsum = 0.f;

    for (int kt = s0; kt < s1; ++kt) {
        const int kbase = kt * 64;
        if (kbase > qwmax) break;   // no barriers: waves independent, tiles ascending

        // ---- scores: S^T[k][q] = K * Q  (K rows direct from L1/L2) ----
        f32x16 st0 = {}, st1 = {};
        PRIO1();
        #pragma unroll
        for (int s = 0; s < 4; ++s) {
            bf16x8 kf0 = *reinterpret_cast<const bf16x8*>(
                Kp + (size_t)(kbase + l31) * 2048 + s * 16 + hi * 8);
            st0 = __builtin_amdgcn_mfma_f32_32x32x16_bf16(kf0, qf[s], st0, 0, 0, 0);
            bf16x8 kf1 = *reinterpret_cast<const bf16x8*>(
                Kp + (size_t)(kbase + 32 + l31) * 2048 + s * 16 + hi * 8);
            st1 = __builtin_amdgcn_mfma_f32_32x32x16_bf16(kf1, qf[s], st1, 0, 0, 0);
        }
        PRIO0();

        // ---- mask + exp2 (m == 0) ----
        float p[32];
        if (kbase + 63 <= q0w) {
            #pragma unroll
            for (int i = 0; i < 16; ++i) { p[i] = st0[i]; p[16 + i] = st1[i]; }
        } else {
            #pragma unroll
            for (int i = 0; i < 16; ++i) {
                int kloc = kbase + (i & 3) + 8 * (i >> 2) + 4 * hi;
                p[i]      = (kloc      <= q) ? st0[i] : -3.0e38f;
                p[16 + i] = (kloc + 32 <= q) ? st1[i] : -3.0e38f;
            }
        }
        #pragma unroll
        for (int i = 0; i < 32; ++i) p[i] = fexp2(p[i]);
        float s0v = 0.f, s1v = 0.f, s2v = 0.f, s3v = 0.f;
        #pragma unroll
        for (int i = 0; i < 8; ++i) {
            s0v += p[4 * i]; s1v += p[4 * i + 1]; s2v += p[4 * i + 2]; s3v += p[4 * i + 3];
        }
        lsum += (s0v + s1v) + (s2v + s3v);

        // ---- P -> bf16 B-frags via permlane32_swap ----
        u32 wds[16];
        #pragma unroll
        for (int j = 0; j < 16; ++j) {
            u16 a = __builtin_bit_cast(u16, (__bf16)p[2 * j]);
            u16 c = __builtin_bit_cast(u16, (__bf16)p[2 * j + 1]);
            wds[j] = (u32)a | ((u32)c << 16);
        }
        union PF { u32 wd[4]; bf16x8 b; } pf[4];
        #pragma unroll
        for (int qd = 0; qd < 4; ++qd) {
            u32 a = wds[4 * qd + 0], bb = wds[4 * qd + 2];
            u32 c = wds[4 * qd + 1], d = wds[4 * qd + 3];
            plswap(a, bb);
            plswap(c, d);
            pf[qd].wd[0] = a; pf[qd].wd[1] = c; pf[qd].wd[2] = bb; pf[qd].wd[3] = d;
        }
        // ---- O^T += K^T * P^T  (V == K; K^T rows direct from L1/L2) ----
        PRIO1();
        #pragma unroll
        for (int kc = 0; kc < 4; ++kc) {
            #pragma unroll
            for (int db = 0; db < 2; ++db) {
                bf16x8 vf = *reinterpret_cast<const bf16x8*>(
                    Tp + (size_t)(db * 32 + l31) * 4096 + kbase + kc * 16 + hi * 8);
                oacc[db] = __builtin_amdgcn_mfma_f32_32x32x16_bf16(vf, pf[kc].b, oacc[db], 0, 0, 0);
            }
        }
        PRIO0();
    }

    lsum += __shfl_xor(lsum, 32);

    if (npc == 1) {
        const float inv = 1.f / lsum;
        u16* op = out + (size_t)(b * 2048 + q) * 1024 + h * 64;
        #pragma unroll
        for (int db = 0; db < 2; ++db) {
            #pragma unroll
            for (int tq = 0; tq < 4; ++tq) {
                ushort4 o;
                o.x = f2bf(oacc[db][tq * 4 + 0] * inv);
                o.y = f2bf(oacc[db][tq * 4 + 1] * inv);
                o.z = f2bf(oacc[db][tq * 4 + 2] * inv);
                o.w = f2bf(oacc[db][tq * 4 + 3] * inv);
                *reinterpret_cast<ushort4*>(op + db * 32 + tq * 8 + hi * 4) = o;
            }
        }
    } else {
        const size_t g = (size_t)bh * 72 + cid;
        u16* po = pO + (g * 128 + (w * 32 + l31)) * 64;
        #pragma unroll
        for (int db = 0; db < 2; ++db) {
            #pragma unroll
            for (int tq = 0; tq < 4; ++tq) {
                ushort4 o;
                o.x = f2bf(oacc[db][tq * 4 + 0]);
                o.y = f2bf(oacc[db][tq * 4 + 1]);
                o.z = f2bf(oacc[db][tq * 4 + 2]);
                o.w = f2bf(oacc[db][tq * 4 + 3]);
                *reinterpret_cast<ushort4*>(po + db * 32 + tq * 8 + hi * 4) = o;
            }
        }
        if (hi == 0)
            pl[g * 128 + w * 32 + l31] = lsum;
    }
}

// ---------------- combine split-k attention partials (q-tiles 2..15) ----------------
__global__ __launch_bounds__(256)
void attn_combine(const u16* __restrict__ pO, const float* __restrict__ pl,
                  u16* __restrict__ out) {
    const int g = blockIdx.x;
    const int bh = g & 31;
    const int qb = 2 + (g >> 5);
    const int b = bh >> 4, h = bh & 15;
    const int base = bh * 72 + CUM2[qb];
    const int npc = CUM2[qb + 1] - CUM2[qb];
    const int t = threadIdx.x;
    const int q = t >> 1;
    const int dh = (t & 1) << 5;

    float L = 0.f;
    float o[32] = {};
    for (int p = 0; p < 8; ++p) {
        if (p >= npc) break;
        L += pl[(size_t)(base + p) * 128 + q];
        const u16* src = pO + ((size_t)(base + p) * 128 + q) * 64 + dh;
        #pragma unroll
        for (int j = 0; j < 8; ++j) {
            ushort4 v = *reinterpret_cast<const ushort4*>(src + j * 4);
            o[4 * j + 0] += bf2f(v.x);
            o[4 * j + 1] += bf2f(v.y);
            o[4 * j + 2] += bf2f(v.z);
            o[4 * j + 3] += bf2f(v.w);
        }
    }
    const float inv = 1.f / L;
    u16* dst = out + ((size_t)(b * 2048 + qb * 128 + q)) * 1024 + h * 64 + dh;
    #pragma unroll
    for (int j = 0; j < 8; ++j) {
        ushort4 w4;
        w4.x = f2bf(o[4 * j + 0] * inv);
        w4.y = f2bf(o[4 * j + 1] * inv);
        w4.z = f2bf(o[4 * j + 2] * inv);
        w4.w = f2bf(o[4 * j + 3] * inv);
        *reinterpret_cast<ushort4*>(dst + j * 4) = w4;
    }
}

// ---------------- launcher ----------------
extern "C" void kernel_launch(void* const* d_in, const int* in_sizes, int n_in,
                              void* d_out, int out_size, void* d_ws, size_t ws_size,
                              hipStream_t stream) {
    const float* x     = (const float*)d_in[0];
    const float* Wq    = (const float*)d_in[1];
    const float* Wk    = (const float*)d_in[2];
    const float* Wproj = (const float*)d_in[3];
    const float* bproj = (const float*)d_in[4];
    const float* ln1g  = (const float*)d_in[5];
    const float* ln1b  = (const float*)d_in[6];
    const float* ln2g  = (const float*)d_in[7];
    const float* ln2b  = (const float*)d_in[8];
    const float* W1    = (const float*)d_in[9];
    const float* b1    = (const float*)d_in[10];
    const float* W2    = (const float*)d_in[11];
    const float* b2    = (const float*)d_in[12];

    char* ws = (char*)d_ws;
    u16*   wqkT   = (u16*)(ws + 0);                     //  4 MiB: 2048x1024
    u16*   wprojT = (u16*)(ws + (4ull << 20));          //  2 MiB
    u16*   w1T    = (u16*)(ws + (6ull << 20));          //  8 MiB: 4096x1024
    u16*   w2T    = (u16*)(ws + (14ull << 20));         //  8 MiB: 1024x4096
    u16*   hbuf   = (u16*)(ws + (22ull << 20));         //  8 MiB
    float* xmid   = (float*)(ws + (30ull << 20));       // 16 MiB fp32
    u16*   qk     = (u16*)(ws + (46ull << 20));         // 16 MiB: 4096x2048
    u16*   ktr    = (u16*)(ws + (62ull << 20));         //  8 MiB: 1024x4096 (K^T)
    u16*   attnb  = (u16*)(ws + (70ull << 20));         //  8 MiB
    u16*   ff     = (u16*)(ws + (46ull << 20));         // 32 MiB, aliases qk+ktr+attnb (dead by then)
    u16*   pO16   = (u16*)(ws + (78ull << 20));         // 37.75 MiB: attn bf16 partials
    u16*   pg     = (u16*)(ws + (78ull << 20));         // gemm bf16 partials (2 x 8 MiB), reuses region
    float* pl     = (float*)(ws + (118ull << 20));      // 1.2 MiB: attn partial l
    const bool fast = ws_size >= (142ull << 20);

    // fused weight prep + LN1
    prep_all<<<6912, 256, 0, stream>>>(Wq, Wk, Wproj, W1, W2,
                                       wqkT, wprojT, w1T, w2T,
                                       x, ln1g, ln1b, hbuf);
    // Q|K projection (Q pre-scaled, K^T side-written) — 256 WGs
    gemmN128<3, u16><<<dim3(16, 16, 1), 512, 0, stream>>>(hbuf, wqkT, qk, 1024, 1024, 2048, ktr);
    // causal attention (V == K)
    if (fast) {
        attn_kernel<1><<<2304, 256, 0, stream>>>(qk, ktr, attnb, pO16, pl);
        attn_combine<<<448, 256, 0, stream>>>(pO16, pl, attnb);
    } else {
        attn_kernel<0><<<512, 256, 0, stream>>>(qk, ktr, attnb, nullptr, nullptr);
    }
    if (fast) {
        // proj: BN=128, split-K=2 -> 256 WGs, bf16 partials; fused reduce+bias+residual+LN2
        gemmN128<0, u16><<<dim3(8, 16, 2), 512, 0, stream>>>(attnb, wprojT, pg, 1024, 512, 1024, nullptr);
        ln2red_kernel<<<4096, 256, 0, stream>>>(
            pg, pg + 4194304, (const float4*)x,
            bproj, ln2g, ln2b, (float4*)xmid, hbuf);
    } else {
        gemm_bt<1, float><<<dim3(8, 32), 256, 0, stream>>>(attnb, wprojT, xmid, bproj, x, 1024, 1024, nullptr);
        ln_kernel<<<4096, 256, 0, stream>>>(xmid, hbuf, ln2g, ln2b);
    }
    // ff = relu(h2 @ W1 + b1)  (bf16 out) — 256 WGs
    gemm256<2, u16><<<dim3(16, 16, 1), 512, 0, stream>>>(hbuf, w1T, ff, b1, nullptr, 1024, 1024, 4096, nullptr);
    // out = xmid + ff @ W2 + b2  (fp32 out)
    if (fast) {
        // W2: BN=128, split-K=2, KC=2048 -> 256 WGs, bf16 partials
        gemmN128<0, u16><<<dim3(8, 16, 2), 512, 0, stream>>>(ff, w2T, pg, 4096, 2048, 1024, nullptr);
        reduce2_kernel<<<4096, 256, 0, stream>>>(
            pg, pg + 4194304, (const float4*)xmid, b2, (float4*)d_out);
    } else {
        gemm_bt<1, float><<<dim3(8, 32), 256, 0, stream>>>(ff, w2T, (float*)d_out, b2, xmid, 4096, 1024, nullptr);
    }
}

// Round 16
// 208.944 us; speedup vs baseline: 1.1751x; 1.1751x over previous
//
#include <hip/hip_runtime.h>
#include <stdint.h>

typedef __bf16 bf16x8 __attribute__((ext_vector_type(8)));
typedef float f32x4 __attribute__((ext_vector_type(4)));
typedef float f32x16 __attribute__((ext_vector_type(16)));
typedef unsigned short u16;
typedef unsigned int u32;
typedef unsigned int u32x2 __attribute__((ext_vector_type(2)));

__device__ __forceinline__ u16 f2bf(float f) {
    u32 u = __builtin_bit_cast(u32, f);
    u = (u + 0x7fffu + ((u >> 16) & 1u)) >> 16;
    return (u16)u;
}
__device__ __forceinline__ float bf2f(u16 x) {
    return __builtin_bit_cast(float, (u32)x << 16);
}
__device__ __forceinline__ float fexp2(float x) {
#if __has_builtin(__builtin_amdgcn_exp2f)
    return __builtin_amdgcn_exp2f(x);
#else
    return exp2f(x);
#endif
}
__device__ __forceinline__ void plswap(u32& a, u32& b) {
#if __has_builtin(__builtin_amdgcn_permlane32_swap)
    u32x2 r = __builtin_amdgcn_permlane32_swap(a, b, false, false);
    a = r[0]; b = r[1];
#else
    asm volatile("v_permlane32_swap_b32 %0, %1" : "+v"(a), "+v"(b));
#endif
}

__device__ __forceinline__ void gload16(const u16* g, u16* l) {
    __builtin_amdgcn_global_load_lds(
        (const __attribute__((address_space(1))) unsigned int*)g,
        (__attribute__((address_space(3))) unsigned int*)l,
        16, 0, 0);
}

// chunk maps for split-k attention: per bh, 72 uniform chunks (<=4 stages of 64 k)
__device__ __constant__ unsigned char QB2[72] = {
    0,1,2,2,3,3,4,4,4,5,5,5,6,6,6,6,7,7,7,7,
    8,8,8,8,8,9,9,9,9,9,10,10,10,10,10,10,11,11,11,11,11,11,
    12,12,12,12,12,12,12,13,13,13,13,13,13,13,
    14,14,14,14,14,14,14,14,15,15,15,15,15,15,15,15};
__device__ __constant__ unsigned char CH2[72] = {
    0,0,0,1,0,1,0,1,2,0,1,2,0,1,2,3,0,1,2,3,
    0,1,2,3,4,0,1,2,3,4,0,1,2,3,4,5,0,1,2,3,4,5,
    0,1,2,3,4,5,6,0,1,2,3,4,5,6,
    0,1,2,3,4,5,6,7,0,1,2,3,4,5,6,7};
__device__ __constant__ unsigned char CUM2[17] =
    {0,1,2,4,6,9,12,16,20,25,30,36,42,49,56,64,72};

// ---------------- fused prep: 5 weight transposes + LN1 ----------------
__global__ __launch_bounds__(256)
void prep_all(const float* __restrict__ Wq, const float* __restrict__ Wk,
              const float* __restrict__ Wproj, const float* __restrict__ W1,
              const float* __restrict__ W2,
              u16* __restrict__ wqkT, u16* __restrict__ wprojT,
              u16* __restrict__ w1T, u16* __restrict__ w2T,
              const float* __restrict__ x, const float* __restrict__ g1,
              const float* __restrict__ b1v, u16* __restrict__ hbuf) {
    __shared__ u16 tile[64 * 64];
    __shared__ float red[8];
    const int bid = blockIdx.x;
    const int t = threadIdx.x;
    if (bid >= 2816) {   // LN1 rows
        const int row = bid - 2816;
        float4 v = reinterpret_cast<const float4*>(x + (size_t)row * 1024)[t];
        float s = v.x + v.y + v.z + v.w;
        float sq = v.x * v.x + v.y * v.y + v.z * v.z + v.w * v.w;
        for (int o = 32; o > 0; o >>= 1) { s += __shfl_down(s, o); sq += __shfl_down(sq, o); }
        if ((t & 63) == 0) { red[t >> 6] = s; red[4 + (t >> 6)] = sq; }
        __syncthreads();
        float S  = red[0] + red[1] + red[2] + red[3];
        float SQ = red[4] + red[5] + red[6] + red[7];
        float mean = S * (1.f / 1024.f);
        float var  = SQ * (1.f / 1024.f) - mean * mean;
        float rstd = rsqrtf(var + 1e-5f);
        float4 g4 = reinterpret_cast<const float4*>(g1)[t];
        float4 b4 = reinterpret_cast<const float4*>(b1v)[t];
        ushort4 o;
        o.x = f2bf((v.x - mean) * rstd * g4.x + b4.x);
        o.y = f2bf((v.y - mean) * rstd * g4.y + b4.y);
        o.z = f2bf((v.z - mean) * rstd * g4.z + b4.z);
        o.w = f2bf((v.w - mean) * rstd * g4.w + b4.w);
        reinterpret_cast<ushort4*>(hbuf + (size_t)row * 1024)[t] = o;
        return;
    }
    const float* src; u16* dst; int R, C, c0, r0; size_t zb = 0;
    if (bid < 512) {
        const int q = bid & 255; const int z = q >> 4;
        src = (bid < 256) ? Wq : Wk;
        dst = (bid < 256) ? wqkT : (wqkT + 1048576);
        R = 1024; C = 64; c0 = 0; r0 = (q & 15) * 64; zb = (size_t)z * 65536;
    } else if (bid < 768) {
        const int q = bid - 512; src = Wproj; dst = wprojT; R = 1024; C = 1024;
        c0 = (q & 15) * 64; r0 = (q >> 4) * 64;
    } else if (bid < 1792) {
        const int q = bid - 768; src = W1; dst = w1T; R = 1024; C = 4096;
        c0 = (q & 63) * 64; r0 = (q >> 6) * 64;
    } else {
        const int q = bid - 1792; src = W2; dst = w2T; R = 4096; C = 1024;
        c0 = (q & 15) * 64; r0 = (q >> 4) * 64;
    }
    {
        const int r = t >> 2, j4 = t & 3;
        #pragma unroll
        for (int j = 0; j < 4; ++j) {
            int c = j4 * 4 + j * 16;
            float4 v = *reinterpret_cast<const float4*>(src + zb + (size_t)(r0 + r) * C + c0 + c);
            tile[(c + 0) * 64 + (r ^ (((c + 0) & 7) * 8))] = f2bf(v.x);
            tile[(c + 1) * 64 + (r ^ (((c + 1) & 7) * 8))] = f2bf(v.y);
            tile[(c + 2) * 64 + (r ^ (((c + 2) & 7) * 8))] = f2bf(v.z);
            tile[(c + 3) * 64 + (r ^ (((c + 3) & 7) * 8))] = f2bf(v.w);
        }
    }
    __syncthreads();
    {
        const int cc = t >> 2, j4 = t & 3;
        const int sw = (cc & 7) * 8;
        #pragma unroll
        for (int j2 = 0; j2 < 4; ++j2) {
            int rbase = j4 * 16 + j2 * 4;
            ushort4 o;
            o.x = tile[cc * 64 + ((rbase + 0) ^ sw)];
            o.y = tile[cc * 64 + ((rbase + 1) ^ sw)];
            o.z = tile[cc * 64 + ((rbase + 2) ^ sw)];
            o.w = tile[cc * 64 + ((rbase + 3) ^ sw)];
            *reinterpret_cast<ushort4*>(dst + zb + (size_t)(c0 + cc) * R + r0 + rbase) = o;
        }
    }
}

// ---------------- layernorm (fallback LN2) ----------------
__global__ __launch_bounds__(256)
void ln_kernel(const float* __restrict__ x, u16* __restrict__ out,
               const float* __restrict__ gw, const float* __restrict__ bw) {
    __shared__ float red[8];
    int row = blockIdx.x, t = threadIdx.x;
    float4 v = reinterpret_cast<const float4*>(x + (size_t)row * 1024)[t];
    float s = v.x + v.y + v.z + v.w;
    float sq = v.x * v.x + v.y * v.y + v.z * v.z + v.w * v.w;
    for (int o = 32; o > 0; o >>= 1) { s += __shfl_down(s, o); sq += __shfl_down(sq, o); }
    if ((t & 63) == 0) { red[t >> 6] = s; red[4 + (t >> 6)] = sq; }
    __syncthreads();
    float S  = red[0] + red[1] + red[2] + red[3];
    float SQ = red[4] + red[5] + red[6] + red[7];
    float mean = S * (1.f / 1024.f);
    float var  = SQ * (1.f / 1024.f) - mean * mean;
    float rstd = rsqrtf(var + 1e-5f);
    float4 g4 = reinterpret_cast<const float4*>(gw)[t];
    float4 b4 = reinterpret_cast<const float4*>(bw)[t];
    ushort4 o;
    o.x = f2bf((v.x - mean) * rstd * g4.x + b4.x);
    o.y = f2bf((v.y - mean) * rstd * g4.y + b4.y);
    o.z = f2bf((v.z - mean) * rstd * g4.z + b4.z);
    o.w = f2bf((v.w - mean) * rstd * g4.w + b4.w);
    reinterpret_cast<ushort4*>(out + (size_t)row * 1024)[t] = o;
}

// ---------------- fused: xmid = bf16(p0)+bf16(p1)+x+bproj ; LN2 -> hbuf bf16 ----------------
__global__ __launch_bounds__(256)
void ln2red_kernel(const u16* __restrict__ p0, const u16* __restrict__ p1,
                   const float4* __restrict__ x4, const float* __restrict__ bproj,
                   const float* __restrict__ gw, const float* __restrict__ bw,
                   float4* __restrict__ xmid, u16* __restrict__ out) {
    __shared__ float red[8];
    const int row = blockIdx.x, t = threadIdx.x;
    const size_t idx = (size_t)row * 256 + t;
    const ushort4 a4 = *reinterpret_cast<const ushort4*>(p0 + idx * 4);
    const ushort4 b4u = *reinterpret_cast<const ushort4*>(p1 + idx * 4);
    float4 xx = x4[idx];
    const float4 bp = *reinterpret_cast<const float4*>(bproj + (t << 2));
    float4 v;
    v.x = bf2f(a4.x) + bf2f(b4u.x) + xx.x + bp.x;
    v.y = bf2f(a4.y) + bf2f(b4u.y) + xx.y + bp.y;
    v.z = bf2f(a4.z) + bf2f(b4u.z) + xx.z + bp.z;
    v.w = bf2f(a4.w) + bf2f(b4u.w) + xx.w + bp.w;
    xmid[idx] = v;
    float s = v.x + v.y + v.z + v.w;
    float sq = v.x * v.x + v.y * v.y + v.z * v.z + v.w * v.w;
    for (int o = 32; o > 0; o >>= 1) { s += __shfl_down(s, o); sq += __shfl_down(sq, o); }
    if ((t & 63) == 0) { red[t >> 6] = s; red[4 + (t >> 6)] = sq; }
    __syncthreads();
    float S  = red[0] + red[1] + red[2] + red[3];
    float SQ = red[4] + red[5] + red[6] + red[7];
    float mean = S * (1.f / 1024.f);
    float var  = SQ * (1.f / 1024.f) - mean * mean;
    float rstd = rsqrtf(var + 1e-5f);
    const float4 g4 = *reinterpret_cast<const float4*>(gw + (t << 2));
    const float4 b4 = *reinterpret_cast<const float4*>(bw + (t << 2));
    ushort4 o;
    o.x = f2bf((v.x - mean) * rstd * g4.x + b4.x);
    o.y = f2bf((v.y - mean) * rstd * g4.y + b4.y);
    o.z = f2bf((v.z - mean) * rstd * g4.z + b4.z);
    o.w = f2bf((v.w - mean) * rstd * g4.w + b4.w);
    *reinterpret_cast<ushort4*>(out + idx * 4) = o;
}

// ---------------- 128x128 GEMM (fallback only) ----------------
template<int EPI, typename OT>
__global__ __launch_bounds__(256)
void gemm_bt(const u16* __restrict__ A, const u16* __restrict__ B,
             OT* __restrict__ C, const float* __restrict__ bias,
             const float* __restrict__ res, int K, int N, u16* __restrict__ ktr) {
    __shared__ u16 Al[128 * 64];
    __shared__ u16 Bl[128 * 64];
    const int t = threadIdx.x;
    const int lane = t & 63;
    const int w = t >> 6;
    const int wm = w >> 1, wn = w & 1;
    const int l15 = lane & 15, gq = lane >> 4;
    const int gx = gridDim.x;
    const int nwg = gx * gridDim.y;
    const int bid = blockIdx.y * gx + blockIdx.x;
    const int sw = ((nwg & 7) == 0) ? ((bid & 7) * (nwg >> 3) + (bid >> 3)) : bid;
    const int col0 = (sw % gx) * 128;
    const int row0 = (sw / gx) * 128;

    f32x4 acc[4][4] = {};

    const int nkb = K >> 6;
    for (int kb = 0; kb < nkb; ++kb) {
        #pragma unroll
        for (int i = 0; i < 4; ++i) {
            int slot = i * 256 + t;
            int r = slot >> 3;
            int g = (slot & 7) ^ (r & 7);
            gload16(A + (size_t)(row0 + r) * K + kb * 64 + g * 8, Al + slot * 8);
            gload16(B + (size_t)(col0 + r) * K + kb * 64 + g * 8, Bl + slot * 8);
        }
        __syncthreads();
        #pragma unroll
        for (int s = 0; s < 2; ++s) {
            bf16x8 af[4], bfr[4];
            #pragma unroll
            for (int mi = 0; mi < 4; ++mi) {
                int rl = wm * 64 + mi * 16 + l15;
                int ba = rl * 128 + ((s * 64 + gq * 16) ^ ((rl & 7) << 4));
                af[mi] = *reinterpret_cast<const bf16x8*>(reinterpret_cast<const char*>(Al) + ba);
            }
            #pragma unroll
            for (int ni = 0; ni < 4; ++ni) {
                int rl = wn * 64 + ni * 16 + l15;
                int ba = rl * 128 + ((s * 64 + gq * 16) ^ ((rl & 7) << 4));
                bfr[ni] = *reinterpret_cast<const bf16x8*>(reinterpret_cast<const char*>(Bl) + ba);
            }
            #pragma unroll
            for (int mi = 0; mi < 4; ++mi)
                #pragma unroll
                for (int ni = 0; ni < 4; ++ni)
                    acc[mi][ni] = __builtin_amdgcn_mfma_f32_16x16x32_bf16(af[mi], bfr[ni], acc[mi][ni], 0, 0, 0);
        }
        __syncthreads();
    }

    #pragma unroll
    for (int mi = 0; mi < 4; ++mi) {
        #pragma unroll
        for (int ni = 0; ni < 4; ++ni) {
            int gcol = col0 + wn * 64 + ni * 16 + l15;
            int grow0 = row0 + wm * 64 + mi * 16 + gq * 4;
            #pragma unroll
            for (int r = 0; r < 4; ++r) {
                int grow = grow0 + r;
                float v = acc[mi][ni][r];
                if constexpr (EPI == 1 || EPI == 2) v += bias[gcol];
                if constexpr (EPI == 1) v += res[(size_t)grow * N + gcol];
                if constexpr (EPI == 2) v = fmaxf(v, 0.f);
                if constexpr (sizeof(OT) == 4) C[(size_t)grow * N + gcol] = v;
                else                           C[(size_t)grow * N + gcol] = f2bf(v);
            }
        }
    }
}

// ---------------- shared macros for fine-phased GEMMs ----------------
#define DS_A(MH) \
  _Pragma("unroll") \
  for (int mi = 0; mi < 4; ++mi) { \
    const int rl = wm * 128 + (MH) * 64 + mi * 16 + l15; \
    const char* rp = abase + rl * 128; \
    const int sw2 = (rl & 7) << 4; \
    af[mi][0] = *reinterpret_cast<const bf16x8*>(rp + ((gq * 16) ^ sw2)); \
    af[mi][1] = *reinterpret_cast<const bf16x8*>(rp + ((64 + gq * 16) ^ sw2)); \
  }

#define DS_B(NH) \
  _Pragma("unroll") \
  for (int ni = 0; ni < 2; ++ni) { \
    const int rl = wn * 64 + (NH) * 32 + ni * 16 + l15; \
    const char* rp = bbase + rl * 128; \
    const int sw2 = (rl & 7) << 4; \
    bfr[NH][ni][0] = *reinterpret_cast<const bf16x8*>(rp + ((gq * 16) ^ sw2)); \
    bfr[NH][ni][1] = *reinterpret_cast<const bf16x8*>(rp + ((64 + gq * 16) ^ sw2)); \
  }

#define ST_A(HALF, KP, DB) \
  _Pragma("unroll") \
  for (int i = 0; i < 2; ++i) { \
    const int idx = i * 512 + t; const int rs = idx >> 3; const int kc = idx & 7; \
    const int row = (rs & 63) + ((rs >> 6) << 7) + (HALF) * 64; \
    gload16(Ag + (size_t)(row0 + row) * Kf + (KP) + ((kc ^ (row & 7)) << 3), (DB) + row * 64 + kc * 8); \
  }

#define ST_B(HALF, KP, DB) \
  _Pragma("unroll") \
  for (int i = 0; i < 2; ++i) { \
    const int idx = i * 512 + t; const int rs = idx >> 3; const int kc = idx & 7; \
    const int row = (rs & 31) + ((rs >> 5) << 6) + (HALF) * 32; \
    gload16(Bg + (size_t)(col0 + row) * Kf + (KP) + ((kc ^ (row & 7)) << 3), (DB) + row * 64 + kc * 8); \
  }

#define MFMA_Q(MH, NH) \
  _Pragma("unroll") \
  for (int mi = 0; mi < 4; ++mi) { \
    _Pragma("unroll") \
    for (int ni = 0; ni < 2; ++ni) { \
      acc[MH][mi][NH][ni] = __builtin_amdgcn_mfma_f32_16x16x32_bf16(af[mi][0], bfr[NH][ni][0], acc[MH][mi][NH][ni], 0, 0, 0); \
      acc[MH][mi][NH][ni] = __builtin_amdgcn_mfma_f32_16x16x32_bf16(af[mi][1], bfr[NH][ni][1], acc[MH][mi][NH][ni], 0, 0, 0); \
    } \
  }

#define WAITV(N) asm volatile("s_waitcnt vmcnt(" #N ")" ::: "memory")
#define BAR() __builtin_amdgcn_s_barrier()
#define PRIO1() __builtin_amdgcn_s_setprio(1)
#define PRIO0() __builtin_amdgcn_s_setprio(0)

// rect-tiled XCD mapping: each XCD's chunk covers a rectangle (L2 locality)
__device__ __forceinline__ void xcd_rect(int bid, int gx, int nwg, int& colI, int& rowI) {
    if (nwg == 256 && gx == 16) {            // 4 cols x 8 rows per XCD
        const int xcd = bid & 7, k = bid >> 3;
        colI = (xcd & 3) * 4 + (k & 3);
        rowI = (xcd >> 2) * 8 + (k >> 2);
    } else if (nwg == 128 && gx == 8) {      // 2 cols x 8 rows per XCD
        const int xcd = bid & 7, k = bid >> 3;
        colI = (xcd & 3) * 2 + (k & 1);
        rowI = (xcd >> 2) * 8 + (k >> 1);
    } else {
        const int sw = ((nwg & 7) == 0) ? ((bid & 7) * (nwg >> 3) + (bid >> 3)) : bid;
        colI = sw % gx; rowI = sw / gx;
    }
}

// ---------------- 256x256 fine-phased GEMM (R8 schedule, B-resident) ----------------
template<int EPI, typename OT>
__global__ __launch_bounds__(512, 2)
void gemm256(const u16* __restrict__ A, const u16* __restrict__ B, OT* __restrict__ C,
             const float* __restrict__ bias, const float* __restrict__ res,
             int Kf, int KC, int N, u16* __restrict__ ktr) {
    __shared__ u16 AL[2][16384];
    __shared__ u16 BL[2][16384];
    const int t = threadIdx.x;
    const int lane = t & 63;
    const int w = t >> 6;
    const int wm = w >> 2, wn = w & 3;
    const int l15 = lane & 15, gq = lane >> 4;
    const int gx = gridDim.x;
    const int nwg = gx * gridDim.y;
    const int bid = blockIdx.y * gx + blockIdx.x;
    int colI, rowI;
    xcd_rect(bid, gx, nwg, colI, rowI);
    const int col0 = colI * 256;
    const int row0 = rowI * 256;
    const int kbase = blockIdx.z * KC;
    const u16* Ag = A;
    const u16* Bg = B;

    f32x4 acc[2][4][2][2] = {};
    bf16x8 af[4][2], bfr[2][2][2];

    const int NT = KC >> 6;
    { u16* An = &AL[0][0]; u16* Bn = &BL[0][0];
      ST_A(0, kbase, An); ST_B(0, kbase, Bn); ST_B(1, kbase, Bn); ST_A(1, kbase, An); }
    WAITV(4);
    BAR();

    for (int tI = 0; tI < NT - 1; ++tI) {
        const int c = tI & 1;
        const char* abase = reinterpret_cast<const char*>(&AL[c][0]);
        const char* bbase = reinterpret_cast<const char*>(&BL[c][0]);
        u16* An = &AL[c ^ 1][0];
        u16* Bn = &BL[c ^ 1][0];
        const int kn = kbase + (tI + 1) * 64;
        // ph1
        DS_A(0); DS_B(0);
        ST_A(0, kn, An);
        WAITV(4); BAR();
        PRIO1(); MFMA_Q(0, 0); PRIO0();
        BAR();
        // ph2
        DS_B(1);
        ST_B(0, kn, Bn);
        WAITV(4); BAR();
        PRIO1(); MFMA_Q(0, 1); PRIO0();
        BAR();
        // ph3 (B half 0 resident in bfr[0])
        DS_A(1);
        ST_B(1, kn, Bn);
        BAR();
        PRIO1(); MFMA_Q(1, 0); PRIO0();
        BAR();
        // ph4 (B half 1 resident in bfr[1])
        ST_A(1, kn, An);
        WAITV(4); BAR();
        PRIO1(); MFMA_Q(1, 1); PRIO0();
        BAR();
    }
    {   // peeled last tile
        const int c = (NT - 1) & 1;
        const char* abase = reinterpret_cast<const char*>(&AL[c][0]);
        const char* bbase = reinterpret_cast<const char*>(&BL[c][0]);
        DS_A(0); DS_B(0);
        WAITV(2); BAR();
        PRIO1(); MFMA_Q(0, 0); PRIO0();
        BAR();
        DS_B(1);
        WAITV(0); BAR();
        PRIO1(); MFMA_Q(0, 1); PRIO0();
        BAR();
        DS_A(1);
        BAR();
        PRIO1(); MFMA_Q(1, 0); PRIO0();
        BAR();
        PRIO1(); MFMA_Q(1, 1); PRIO0();
    }

    const size_t Crow0 = (size_t)blockIdx.z * ((size_t)gridDim.y * 256);
    #pragma unroll
    for (int mh = 0; mh < 2; ++mh)
    #pragma unroll
    for (int mi = 0; mi < 4; ++mi)
    #pragma unroll
    for (int nh = 0; nh < 2; ++nh)
    #pragma unroll
    for (int ni = 0; ni < 2; ++ni) {
        const int gcol = col0 + wn * 64 + nh * 32 + ni * 16 + l15;
        const int grow0 = row0 + wm * 128 + mh * 64 + mi * 16 + gq * 4;
        f32x4 v = acc[mh][mi][nh][ni];
        if constexpr (EPI == 2) {
            const float bb = bias[gcol];
            v[0] += bb; v[1] += bb; v[2] += bb; v[3] += bb;
        }
        #pragma unroll
        for (int r = 0; r < 4; ++r) {
            const size_t o = (Crow0 + grow0 + r) * N + gcol;
            float x = v[r];
            if constexpr (EPI == 2) x = fmaxf(x, 0.f);
            if constexpr (sizeof(OT) == 4) C[o] = x;
            else                           C[o] = f2bf(x);
        }
    }
}

// ---------------- 256x128 fine-phased GEMM (R8 schedule) ----------------
#define DS_B2 \
  _Pragma("unroll") \
  for (int ni = 0; ni < 2; ++ni) { \
    const int rl = wn * 32 + ni * 16 + l15; \
    const char* rp = bbase + rl * 128; \
    const int sw2 = (rl & 7) << 4; \
    bfr[ni][0] = *reinterpret_cast<const bf16x8*>(rp + ((gq * 16) ^ sw2)); \
    bfr[ni][1] = *reinterpret_cast<const bf16x8*>(rp + ((64 + gq * 16) ^ sw2)); \
  }

#define ST_B2(KP, DB) \
  _Pragma("unroll") \
  for (int i = 0; i < 2; ++i) { \
    const int idx = i * 512 + t; const int rs = idx >> 3; const int kc = idx & 7; \
    gload16(Bg + (size_t)(col0 + rs) * Kf + (KP) + ((kc ^ (rs & 7)) << 3), (DB) + rs * 64 + kc * 8); \
  }

#define MFMA_Q2(MH) \
  _Pragma("unroll") \
  for (int mi = 0; mi < 4; ++mi) { \
    _Pragma("unroll") \
    for (int ni = 0; ni < 2; ++ni) { \
      acc[MH][mi][ni] = __builtin_amdgcn_mfma_f32_16x16x32_bf16(af[mi][0], bfr[ni][0], acc[MH][mi][ni], 0, 0, 0); \
      acc[MH][mi][ni] = __builtin_amdgcn_mfma_f32_16x16x32_bf16(af[mi][1], bfr[ni][1], acc[MH][mi][ni], 0, 0, 0); \
    } \
  }

template<int EPI, typename OT>
__global__ __launch_bounds__(512, 2)
void gemmN128(const u16* __restrict__ A, const u16* __restrict__ B, OT* __restrict__ C,
              int Kf, int KC, int N, u16* __restrict__ ktr) {
    __shared__ u16 AL[2][16384];   // 256 x 64
    __shared__ u16 BL[2][8192];    // 128 x 64
    const int t = threadIdx.x;
    const int lane = t & 63;
    const int w = t >> 6;
    const int wm = w >> 2, wn = w & 3;
    const int l15 = lane & 15, gq = lane >> 4;
    const int gx = gridDim.x;
    const int nwg = gx * gridDim.y;
    const int bid = blockIdx.y * gx + blockIdx.x;
    int colI, rowI;
    xcd_rect(bid, gx, nwg, colI, rowI);
    const int col0 = colI * 128;
    const int row0 = rowI * 256;
    const int kbase = blockIdx.z * KC;
    const u16* Ag = A;
    const u16* Bg = B;

    f32x4 acc[2][4][2] = {};
    bf16x8 af[4][2], bfr[2][2];

    const int NT = KC >> 6;
    { u16* An = &AL[0][0]; u16* Bn = &BL[0][0];
      ST_A(0, kbase, An); ST_B2(kbase, Bn); ST_A(1, kbase, An); }
    WAITV(0);
    BAR();

    for (int tI = 0; tI < NT - 1; ++tI) {
        const int c = tI & 1;
        const char* abase = reinterpret_cast<const char*>(&AL[c][0]);
        const char* bbase = reinterpret_cast<const char*>(&BL[c][0]);
        u16* An = &AL[c ^ 1][0];
        u16* Bn = &BL[c ^ 1][0];
        const int kn = kbase + (tI + 1) * 64;
        // ph1
        DS_A(0); DS_B2;
        ST_A(0, kn, An); ST_B2(kn, Bn);
        WAITV(4); BAR();
        PRIO1(); MFMA_Q2(0); PRIO0();
        BAR();
        // ph2
        DS_A(1);
        ST_A(1, kn, An);
        WAITV(2); BAR();
        PRIO1(); MFMA_Q2(1); PRIO0();
        BAR();
    }
    {   // peeled last tile
        const int c = (NT - 1) & 1;
        const char* abase = reinterpret_cast<const char*>(&AL[c][0]);
        const char* bbase = reinterpret_cast<const char*>(&BL[c][0]);
        DS_A(0); DS_B2;
        WAITV(0); BAR();
        PRIO1(); MFMA_Q2(0); PRIO0();
        BAR();
        DS_A(1);
        PRIO1(); MFMA_Q2(1); PRIO0();
    }

    const size_t Crow0 = (size_t)blockIdx.z * ((size_t)gridDim.y * 256);
    #pragma unroll
    for (int mh = 0; mh < 2; ++mh)
    #pragma unroll
    for (int mi = 0; mi < 4; ++mi)
    #pragma unroll
    for (int ni = 0; ni < 2; ++ni) {
        const int gcol = col0 + wn * 32 + ni * 16 + l15;
        const int grow0 = row0 + wm * 128 + mh * 64 + mi * 16 + gq * 4;
        f32x4 v = acc[mh][mi][ni];
        if constexpr (EPI == 3) {
            if (gcol < 1024) {   // Q columns: fold 1/sqrt(Dh) * log2(e) into Q
                const float QS = 0.18033688f;
                v[0] *= QS; v[1] *= QS; v[2] *= QS; v[3] *= QS;
            }
        }
        #pragma unroll
        for (int r = 0; r < 4; ++r) {
            const size_t o = (Crow0 + grow0 + r) * N + gcol;
            if constexpr (sizeof(OT) == 4) C[o] = v[r];
            else                           C[o] = f2bf(v[r]);
        }
        if constexpr (EPI == 3) {
            if (gcol >= 1024) {
                ushort4 k4;
                k4.x = f2bf(v[0]); k4.y = f2bf(v[1]); k4.z = f2bf(v[2]); k4.w = f2bf(v[3]);
                *reinterpret_cast<ushort4*>(ktr + (size_t)(gcol - 1024) * 4096 + grow0) = k4;
            }
        }
    }
}

// ---------------- split-K=2 reduce (bf16 partials): out = xmid + b2 + p0 + p1 ----------------
__global__ __launch_bounds__(256)
void reduce2_kernel(const u16* __restrict__ p0, const u16* __restrict__ p1,
                    const float4* __restrict__ xm, const float* __restrict__ b2,
                    float4* __restrict__ out) {
    const size_t i = (size_t)blockIdx.x * 256 + threadIdx.x;
    const ushort4 a4 = *reinterpret_cast<const ushort4*>(p0 + i * 4);
    const ushort4 b4 = *reinterpret_cast<const ushort4*>(p1 + i * 4);
    float4 x = xm[i];
    const float4 bb = *reinterpret_cast<const float4*>(b2 + ((threadIdx.x & 255) << 2));
    float4 o;
    o.x = x.x + bb.x + bf2f(a4.x) + bf2f(b4.x);
    o.y = x.y + bb.y + bf2f(a4.y) + bf2f(b4.y);
    o.z = x.z + bb.z + bf2f(a4.z) + bf2f(b4.z);
    o.w = x.w + bb.w + bf2f(a4.w) + bf2f(b4.w);
    out[i] = o;
}

// ---------------- causal flash attention, V == K, uniform split-k chunks ----------------
template<int SPLIT>
__global__ __launch_bounds__(256)
void attn_kernel(const u16* __restrict__ qk, const u16* __restrict__ ktr, u16* __restrict__ out,
                 u16* __restrict__ pO, float* __restrict__ pl) {
    __shared__ u16 Kl[2][64 * 64];   // K rows  [k][d], swizzled
    __shared__ u16 Tl[2][64 * 64];   // K^T     [d][k], swizzled
    const int t = threadIdx.x;
    const int lane = t & 63;
    const int w = t >> 6;
    const int l31 = lane & 31, hi = lane >> 5;
    int bh, qb, npc, cid, s0, s1;
    if constexpr (SPLIT) {
        bh = blockIdx.x & 31;
        cid = blockIdx.x >> 5;
        qb = QB2[cid];
        const int ch = CH2[cid];
        npc = CUM2[qb + 1] - CUM2[qb];
        const int nt = 2 * (qb + 1);
        s0 = ch * 4;
        s1 = min(nt, s0 + 4);
    } else {
        bh = blockIdx.x & 31;
        const int tt = blockIdx.x >> 5;
        qb = (tt < 8) ? tt : 23 - tt;
        cid = 0; npc = 1; s0 = 0; s1 = 2 * (qb + 1);
    }
    const int b = bh >> 4, h = bh & 15;
    const int q0w = qb * 128 + w * 32;
    const int q = q0w + l31;
    const int qwmax = q0w + 31;
    const u16* Qp = qk + (size_t)b * 2048 * 2048 + h * 64;
    const u16* Kp = Qp + 1024;
    const u16* Tp = ktr + (size_t)h * 64 * 4096 + (size_t)b * 2048;

    bf16x8 qf[4];
    #pragma unroll
    for (int s = 0; s < 4; ++s)
        qf[s] = *reinterpret_cast<const bf16x8*>(Qp + (size_t)q * 2048 + s * 16 + hi * 8);

    f32x16 oacc[2] = {};
    float lsum = 0.f;

    {   // stage first tile
        #pragma unroll
        for (int i = 0; i < 2; ++i) {
            int slot = i * 256 + t;
            int r = slot >> 3;
            int g = (slot & 7) ^ (r & 7);
            gload16(Kp + (size_t)(s0 * 64 + r) * 2048 + g * 8, &Kl[0][0] + slot * 8);
            gload16(Tp + (size_t)r * 4096 + s0 * 64 + g * 8, &Tl[0][0] + slot * 8);
        }
    }

    for (int kt = s0; kt < s1; ++kt) {
        const int cur = (kt - s0) & 1;
        __syncthreads();
        if (kt + 1 < s1) {
            int k0 = (kt + 1) * 64;
            #pragma unroll
            for (int i = 0; i < 2; ++i) {
                int slot = i * 256 + t;
                int r = slot >> 3;
                int g = (slot & 7) ^ (r & 7);
                gload16(Kp + (size_t)(k0 + r) * 2048 + g * 8, &Kl[cur ^ 1][0] + slot * 8);
                gload16(Tp + (size_t)r * 4096 + k0 + g * 8, &Tl[cur ^ 1][0] + slot * 8);
            }
        }
        const int kbase = kt * 64;
        if (kbase > qwmax) continue;
        const u16* kl = &Kl[cur][0];
        const u16* tl = &Tl[cur][0];

        // ---- scores: S^T[k][q] = K * Q ----
        f32x16 st0 = {}, st1 = {};
        PRIO1();
        #pragma unroll
        for (int s = 0; s < 4; ++s) {
            {
                int r = l31;
                int col = (16 * s + 8 * hi) ^ ((r & 7) * 8);
                bf16x8 kf = *reinterpret_cast<const bf16x8*>(kl + r * 64 + col);
                st0 = __builtin_amdgcn_mfma_f32_32x32x16_bf16(kf, qf[s], st0, 0, 0, 0);
            }
            {
                int r = 32 + l31;
                int col = (16 * s + 8 * hi) ^ ((r & 7) * 8);
                bf16x8 kf = *reinterpret_cast<const bf16x8*>(kl + r * 64 + col);
                st1 = __builtin_amdgcn_mfma_f32_32x32x16_bf16(kf, qf[s], st1, 0, 0, 0);
            }
        }
        PRIO0();

        // ---- mask + exp2 (m == 0) ----
        float p[32];
        if (kbase + 63 <= q0w) {
            #pragma unroll
            for (int i = 0; i < 16; ++i) { p[i] = st0[i]; p[16 + i] = st1[i]; }
        } else {
            #pragma unroll
            for (int i = 0; i < 16; ++i) {
                int kloc = kbase + (i & 3) + 8 * (i >> 2) + 4 * hi;
                p[i]      = (kloc      <= q) ? st0[i] : -3.0e38f;
                p[16 + i] = (kloc + 32 <= q) ? st1[i] : -3.0e38f;
            }
        }
        #pragma unroll
        for (int i = 0; i < 32; ++i) p[i] = fexp2(p[i]);
        float s0v = 0.f, s1v = 0.f, s2v = 0.f, s3v = 0.f;
        #pragma unroll
        for (int i = 0; i < 8; ++i) {
            s0v += p[4 * i]; s1v += p[4 * i + 1]; s2v += p[4 * i + 2]; s3v += p[4 * i + 3];
        }
        lsum += (s0v + s1v) + (s2v + s3v);

        // ---- P -> bf16 B-frags via permlane32_swap ----
        u32 wds[16];
        #pragma unroll
        for (int j = 0; j < 16; ++j) {
            u16 a = __builtin_bit_cast(u16, (__bf16)p[2 * j]);
            u16 c = __builtin_bit_cast(u16, (__bf16)p[2 * j + 1]);
            wds[j] = (u32)a | ((u32)c << 16);
        }
        union PF { u32 wd[4]; bf16x8 b; } pf[4];
        #pragma unroll
        for (int qd = 0; qd < 4; ++qd) {
            u32 a = wds[4 * qd + 0], bb = wds[4 * qd + 2];
            u32 c = wds[4 * qd + 1], d = wds[4 * qd + 3];
            plswap(a, bb);
            plswap(c, d);
            pf[qd].wd[0] = a; pf[qd].wd[1] = c; pf[qd].wd[2] = bb; pf[qd].wd[3] = d;
        }
        // ---- O^T += K^T * P^T  (V == K) ----
        PRIO1();
        #pragma unroll
        for (int kc = 0; kc < 4; ++kc) {
            #pragma unroll
            for (int db = 0; db < 2; ++db) {
                int r = db * 32 + l31;
                int col = (kc * 16 + 8 * hi) ^ ((r & 7) * 8);
                bf16x8 vf = *reinterpret_cast<const bf16x8*>(tl + r * 64 + col);
                oacc[db] = __builtin_amdgcn_mfma_f32_32x32x16_bf16(vf, pf[kc].b, oacc[db], 0, 0, 0);
            }
        }
        PRIO0();
    }

    lsum += __shfl_xor(lsum, 32);

    if (npc == 1) {
        const float inv = 1.f / lsum;
        u16* op = out + (size_t)(b * 2048 + q) * 1024 + h * 64;
        #pragma unroll
        for (int db = 0; db < 2; ++db) {
            #pragma unroll
            for (int tq = 0; tq < 4; ++tq) {
                ushort4 o;
                o.x = f2bf(oacc[db][tq * 4 + 0] * inv);
                o.y = f2bf(oacc[db][tq * 4 + 1] * inv);
                o.z = f2bf(oacc[db][tq * 4 + 2] * inv);
                o.w = f2bf(oacc[db][tq * 4 + 3] * inv);
                *reinterpret_cast<ushort4*>(op + db * 32 + tq * 8 + hi * 4) = o;
            }
        }
    } else {
        const size_t g = (size_t)bh * 72 + cid;
        u16* po = pO + (g * 128 + (w * 32 + l31)) * 64;
        #pragma unroll
        for (int db = 0; db < 2; ++db) {
            #pragma unroll
            for (int tq = 0; tq < 4; ++tq) {
                ushort4 o;
                o.x = f2bf(oacc[db][tq * 4 + 0]);
                o.y = f2bf(oacc[db][tq * 4 + 1]);
                o.z = f2bf(oacc[db][tq * 4 + 2]);
                o.w = f2bf(oacc[db][tq * 4 + 3]);
                *reinterpret_cast<ushort4*>(po + db * 32 + tq * 8 + hi * 4) = o;
            }
        }
        if (hi == 0)
            pl[g * 128 + w * 32 + l31] = lsum;
    }
}

// ---------------- combine split-k attention partials (q-tiles 2..15) ----------------
__global__ __launch_bounds__(256)
void attn_combine(const u16* __restrict__ pO, const float* __restrict__ pl,
                  u16* __restrict__ out) {
    const int g = blockIdx.x;
    const int bh = g & 31;
    const int qb = 2 + (g >> 5);
    const int b = bh >> 4, h = bh & 15;
    const int base = bh * 72 + CUM2[qb];
    const int npc = CUM2[qb + 1] - CUM2[qb];
    const int t = threadIdx.x;
    const int q = t >> 1;
    const int dh = (t & 1) << 5;

    float L = 0.f;
    float o[32] = {};
    for (int p = 0; p < 8; ++p) {
        if (p >= npc) break;
        L += pl[(size_t)(base + p) * 128 + q];
        const u16* src = pO + ((size_t)(base + p) * 128 + q) * 64 + dh;
        #pragma unroll
        for (int j = 0; j < 8; ++j) {
            ushort4 v = *reinterpret_cast<const ushort4*>(src + j * 4);
            o[4 * j + 0] += bf2f(v.x);
            o[4 * j + 1] += bf2f(v.y);
            o[4 * j + 2] += bf2f(v.z);
            o[4 * j + 3] += bf2f(v.w);
        }
    }
    const float inv = 1.f / L;
    u16* dst = out + ((size_t)(b * 2048 + qb * 128 + q)) * 1024 + h * 64 + dh;
    #pragma unroll
    for (int j = 0; j < 8; ++j) {
        ushort4 w4;
        w4.x = f2bf(o[4 * j + 0] * inv);
        w4.y = f2bf(o[4 * j + 1] * inv);
        w4.z = f2bf(o[4 * j + 2] * inv);
        w4.w = f2bf(o[4 * j + 3] * inv);
        *reinterpret_cast<ushort4*>(dst + j * 4) = w4;
    }
}

// ---------------- launcher ----------------
extern "C" void kernel_launch(void* const* d_in, const int* in_sizes, int n_in,
                              void* d_out, int out_size, void* d_ws, size_t ws_size,
                              hipStream_t stream) {
    const float* x     = (const float*)d_in[0];
    const float* Wq    = (const float*)d_in[1];
    const float* Wk    = (const float*)d_in[2];
    const float* Wproj = (const float*)d_in[3];
    const float* bproj = (const float*)d_in[4];
    const float* ln1g  = (const float*)d_in[5];
    const float* ln1b  = (const float*)d_in[6];
    const float* ln2g  = (const float*)d_in[7];
    const float* ln2b  = (const float*)d_in[8];
    const float* W1    = (const float*)d_in[9];
    const float* b1    = (const float*)d_in[10];
    const float* W2    = (const float*)d_in[11];
    const float* b2    = (const float*)d_in[12];

    char* ws = (char*)d_ws;
    u16*   wqkT   = (u16*)(ws + 0);                     //  4 MiB: 2048x1024
    u16*   wprojT = (u16*)(ws + (4ull << 20));          //  2 MiB
    u16*   w1T    = (u16*)(ws + (6ull << 20));          //  8 MiB: 4096x1024
    u16*   w2T    = (u16*)(ws + (14ull << 20));         //  8 MiB: 1024x4096
    u16*   hbuf   = (u16*)(ws + (22ull << 20));         //  8 MiB
    float* xmid   = (float*)(ws + (30ull << 20));       // 16 MiB fp32
    u16*   qk     = (u16*)(ws + (46ull << 20));         // 16 MiB: 4096x2048
    u16*   ktr    = (u16*)(ws + (62ull << 20));         //  8 MiB: 1024x4096 (K^T)
    u16*   attnb  = (u16*)(ws + (70ull << 20));         //  8 MiB
    u16*   ff     = (u16*)(ws + (46ull << 20));         // 32 MiB, aliases qk+ktr+attnb (dead by then)
    u16*   pO16   = (u16*)(ws + (78ull << 20));         // 37.75 MiB: attn bf16 partials
    u16*   pg     = (u16*)(ws + (78ull << 20));         // gemm bf16 partials (2 x 8 MiB), reuses region
    float* pl     = (float*)(ws + (118ull << 20));      // 1.2 MiB: attn partial l
    const bool fast = ws_size >= (142ull << 20);

    // fused weight prep + LN1
    prep_all<<<6912, 256, 0, stream>>>(Wq, Wk, Wproj, W1, W2,
                                       wqkT, wprojT, w1T, w2T,
                                       x, ln1g, ln1b, hbuf);
    // Q|K projection (Q pre-scaled, K^T side-written) — 256 WGs
    gemmN128<3, u16><<<dim3(16, 16, 1), 512, 0, stream>>>(hbuf, wqkT, qk, 1024, 1024, 2048, ktr);
    // causal attention (V == K)
    if (fast) {
        attn_kernel<1><<<2304, 256, 0, stream>>>(qk, ktr, attnb, pO16, pl);
        attn_combine<<<448, 256, 0, stream>>>(pO16, pl, attnb);
    } else {
        attn_kernel<0><<<512, 256, 0, stream>>>(qk, ktr, attnb, nullptr, nullptr);
    }
    if (fast) {
        // proj: BN=128, split-K=2 -> 256 WGs, bf16 partials; fused reduce+bias+residual+LN2
        gemmN128<0, u16><<<dim3(8, 16, 2), 512, 0, stream>>>(attnb, wprojT, pg, 1024, 512, 1024, nullptr);
        ln2red_kernel<<<4096, 256, 0, stream>>>(
            pg, pg + 4194304, (const float4*)x,
            bproj, ln2g, ln2b, (float4*)xmid, hbuf);
    } else {
        gemm_bt<1, float><<<dim3(8, 32), 256, 0, stream>>>(attnb, wprojT, xmid, bproj, x, 1024, 1024, nullptr);
        ln_kernel<<<4096, 256, 0, stream>>>(xmid, hbuf, ln2g, ln2b);
    }
    // ff = relu(h2 @ W1 + b1)  (bf16 out) — 256 WGs
    gemm256<2, u16><<<dim3(16, 16, 1), 512, 0, stream>>>(hbuf, w1T, ff, b1, nullptr, 1024, 1024, 4096, nullptr);
    // out = xmid + ff @ W2 + b2  (fp32 out)
    if (fast) {
        // W2: BN=128, split-K=2, KC=2048 -> 256 WGs, bf16 partials
        gemmN128<0, u16><<<dim3(8, 16, 2), 512, 0, stream>>>(ff, w2T, pg, 4096, 2048, 1024, nullptr);
        reduce2_kernel<<<4096, 256, 0, stream>>>(
            pg, pg + 4194304, (const float4*)xmid, b2, (float4*)d_out);
    } else {
        gemm_bt<1, float><<<dim3(8, 32), 256, 0, stream>>>(ff, w2T, (float*)d_out, b2, xmid, 4096, 1024, nullptr);
    }
}